// Round 1
// baseline (640.182 us; speedup 1.0000x reference)
//
#include <hip/hip_runtime.h>

// Problem constants (reference: N=65536, D=512, S=262144)
#define NROWS 65536
#define DCOLS 512
#define D4    128   // float4 per row

// Native 16B vector type usable with __builtin_nontemporal_store
typedef float f32x4 __attribute__((ext_vector_type(4)));

// ---------------------------------------------------------------------------
// Kernel 1: inclusive prefix sum of feeds_repeat_times (N=65536) into cum[].
// Single block: 1024 threads x 64 elements each. Per-thread sequential scan,
// Hillis-Steele over 1024 partials in LDS, then add exclusive offset.
// (Unchanged from the verified version — measured small relative to gather.)
// ---------------------------------------------------------------------------
__global__ __launch_bounds__(1024) void scan_kernel(const int* __restrict__ rep,
                                                    int* __restrict__ cum) {
    __shared__ int sdata[1024];
    const int t = threadIdx.x;
    const int base = t * 64;

    int4 v[16];
    const int4* rep4 = (const int4*)(rep + base);
#pragma unroll
    for (int k = 0; k < 16; ++k) v[k] = rep4[k];

    int partial = 0;
#pragma unroll
    for (int k = 0; k < 16; ++k) partial += v[k].x + v[k].y + v[k].z + v[k].w;

    sdata[t] = partial;
    __syncthreads();
    for (int off = 1; off < 1024; off <<= 1) {
        int add = (t >= off) ? sdata[t - off] : 0;
        __syncthreads();
        sdata[t] += add;
        __syncthreads();
    }
    int running = sdata[t] - partial;  // exclusive prefix of this thread's chunk

    int4* cum4 = (int4*)(cum + base);
#pragma unroll
    for (int k = 0; k < 16; ++k) {
        int4 x;
        running += v[k].x; x.x = running;
        running += v[k].y; x.y = running;
        running += v[k].z; x.z = running;
        running += v[k].w; x.w = running;
        cum4[k] = x;
    }
}

// ---------------------------------------------------------------------------
// Kernel 2: source-row-centric expand. One wave (64 lanes) per SOURCE row.
// Load the 2 KB row ONCE into registers (2 x f32x4 per lane), then store it
// r times to the contiguous output rows [cum[i]-r, cum[i]) (truncated at S).
// Feeds is thus read exactly once, as a pure sequential 128 MiB stream —
// no L2/L3 re-reads, no idx array, no per-output-row index load.
// The zero padding tail [total, S) is distributed across waves (stride NROWS).
// Nontemporal stores keep the 512 MiB output stream out of the caches.
// ---------------------------------------------------------------------------
__global__ __launch_bounds__(256) void expand_kernel(const f32x4* __restrict__ feeds,
                                                     const int* __restrict__ rep,
                                                     const int* __restrict__ cum,
                                                     f32x4* __restrict__ out,
                                                     int S) {
    const int wave = (int)((blockIdx.x * blockDim.x + threadIdx.x) >> 6);
    const int lane = threadIdx.x & 63;

    const int i     = wave;                 // source row
    const int end   = cum[i];
    const int r     = rep[i];
    const int start = end - r;
    const int stop  = end < S ? end : S;

    if (start < stop) {
        const f32x4* src = feeds + (long long)i * D4;
        const f32x4 a = src[lane];
        const f32x4 b = src[lane + 64];
        for (int j = start; j < stop; ++j) {
            f32x4* dst = out + (long long)j * D4;
            __builtin_nontemporal_store(a, dst + lane);
            __builtin_nontemporal_store(b, dst + lane + 64);
        }
    }

    // Zero the padding tail [total, S): wave w owns rows total+w, total+w+NROWS, ...
    const int total = cum[NROWS - 1];
    const f32x4 z = (f32x4)0.f;
    for (int j = total + wave; j < S; j += NROWS) {
        f32x4* dst = out + (long long)j * D4;
        __builtin_nontemporal_store(z, dst + lane);
        __builtin_nontemporal_store(z, dst + lane + 64);
    }
}

extern "C" void kernel_launch(void* const* d_in, const int* in_sizes, int n_in,
                              void* d_out, int out_size, void* d_ws, size_t ws_size,
                              hipStream_t stream) {
    const float* feeds = (const float*)d_in[0];
    const int*   rep   = (const int*)d_in[1];
    const int S = out_size / DCOLS;

    int* cum = (int*)d_ws;  // 65536 ints = 256 KB

    scan_kernel<<<1, 1024, 0, stream>>>(rep, cum);
    // One wave per source row: NROWS waves -> NROWS*64 threads / 256 = NROWS/4 blocks.
    expand_kernel<<<NROWS / 4, 256, 0, stream>>>((const f32x4*)feeds, rep, cum,
                                                 (f32x4*)d_out, S);
}

// Round 2
// 630.367 us; speedup vs baseline: 1.0156x; 1.0156x over previous
//
#include <hip/hip_runtime.h>

// Problem constants (reference: N=65536, D=512, S=262144)
#define NROWS 65536
#define DCOLS 512
#define D4    128   // float4 per row

typedef float f32x4 __attribute__((ext_vector_type(4)));

// ---------------------------------------------------------------------------
// Kernel 1: inclusive prefix sum of feeds_repeat_times (N=65536) into cum[].
// Single block: 1024 threads x 64 elements each. Per-thread sequential scan,
// Hillis-Steele over 1024 partials in LDS, then add exclusive offset.
// ---------------------------------------------------------------------------
__global__ __launch_bounds__(1024) void scan_kernel(const int* __restrict__ rep,
                                                    int* __restrict__ cum) {
    __shared__ int sdata[1024];
    const int t = threadIdx.x;
    const int base = t * 64;

    int4 v[16];
    const int4* rep4 = (const int4*)(rep + base);
#pragma unroll
    for (int k = 0; k < 16; ++k) v[k] = rep4[k];

    int partial = 0;
#pragma unroll
    for (int k = 0; k < 16; ++k) partial += v[k].x + v[k].y + v[k].z + v[k].w;

    sdata[t] = partial;
    __syncthreads();
    for (int off = 1; off < 1024; off <<= 1) {
        int add = (t >= off) ? sdata[t - off] : 0;
        __syncthreads();
        sdata[t] += add;
        __syncthreads();
    }
    int running = sdata[t] - partial;  // exclusive prefix of this thread's chunk

    int4* cum4 = (int4*)(cum + base);
#pragma unroll
    for (int k = 0; k < 16; ++k) {
        int4 x;
        running += v[k].x; x.x = running;
        running += v[k].y; x.y = running;
        running += v[k].z; x.z = running;
        running += v[k].w; x.w = running;
        cum4[k] = x;
    }
}

// ---------------------------------------------------------------------------
// Kernel 2: source-row-centric expand. One wave (64 lanes) per SOURCE row.
// Load the 2 KB row ONCE into registers (2 x f32x4 per lane), then store it
// r times to the contiguous output rows [cum[i]-r, cum[i)) (truncated at S).
//
// ROUND-2 CHANGE (single variable): plain stores instead of
// __builtin_nontemporal_store. Theory: nt's no-allocate policy bypasses
// L2/L3 write combining/buffering and caps the write stream at ~2.1 TB/s;
// the harness's plain-store fill proves 6.2 TB/s is reachable. The original
// "keep feeds L3-resident" rationale is void: feeds is read exactly once
// here, and the 2 GiB poison fill evicts L3 between iterations anyway.
// ---------------------------------------------------------------------------
__global__ __launch_bounds__(256) void expand_kernel(const f32x4* __restrict__ feeds,
                                                     const int* __restrict__ rep,
                                                     const int* __restrict__ cum,
                                                     f32x4* __restrict__ out,
                                                     int S) {
    const int wave = (int)((blockIdx.x * blockDim.x + threadIdx.x) >> 6);
    const int lane = threadIdx.x & 63;

    const int i     = wave;                 // source row
    const int end   = cum[i];
    const int r     = rep[i];
    const int start = end - r;
    const int stop  = end < S ? end : S;

    if (start < stop) {
        const f32x4* src = feeds + (long long)i * D4;
        const f32x4 a = src[lane];
        const f32x4 b = src[lane + 64];
        for (int j = start; j < stop; ++j) {
            f32x4* dst = out + (long long)j * D4;
            dst[lane]      = a;
            dst[lane + 64] = b;
        }
    }

    // Zero the padding tail [total, S): wave w owns rows total+w, total+w+NROWS, ...
    const int total = cum[NROWS - 1];
    const f32x4 z = (f32x4)0.f;
    for (int j = total + wave; j < S; j += NROWS) {
        f32x4* dst = out + (long long)j * D4;
        dst[lane]      = z;
        dst[lane + 64] = z;
    }
}

extern "C" void kernel_launch(void* const* d_in, const int* in_sizes, int n_in,
                              void* d_out, int out_size, void* d_ws, size_t ws_size,
                              hipStream_t stream) {
    const float* feeds = (const float*)d_in[0];
    const int*   rep   = (const int*)d_in[1];
    const int S = out_size / DCOLS;

    int* cum = (int*)d_ws;  // 65536 ints = 256 KB

    scan_kernel<<<1, 1024, 0, stream>>>(rep, cum);
    // One wave per source row: NROWS waves -> NROWS*64 threads / 256 = NROWS/4 blocks.
    expand_kernel<<<NROWS / 4, 256, 0, stream>>>((const f32x4*)feeds, rep, cum,
                                                 (f32x4*)d_out, S);
}

// Round 3
// 620.370 us; speedup vs baseline: 1.0319x; 1.0161x over previous
//
#include <hip/hip_runtime.h>

// Problem constants (reference: N=65536, D=512, S=262144)
#define NROWS 65536
#define DCOLS 512
#define D4    128   // float4 per row
#define CHUNK 256   // rows per scan chunk
#define NCHUNK (NROWS / CHUNK)  // 256 chunks

typedef float f32x4 __attribute__((ext_vector_type(4)));

// ---------------------------------------------------------------------------
// Workspace layout (ints):
//   [0      .. 255 ]  chunksum[256]
//   [256    .. 511 ]  chunkoff[256]   (exclusive prefix of chunksum)
//   [512           ]  total
//   [1024   .. ... ]  idx16[S]  (unsigned short, 512 KB)
// ---------------------------------------------------------------------------

// K1: per-chunk sums of rep. 256 blocks x 256 threads, 1 int/thread.
__global__ __launch_bounds__(256) void chunk_sum_kernel(const int* __restrict__ rep,
                                                        int* __restrict__ chunksum) {
    const int b = blockIdx.x;
    const int t = threadIdx.x;
    int v = rep[b * CHUNK + t];
#pragma unroll
    for (int off = 32; off; off >>= 1) v += __shfl_down(v, off);
    __shared__ int ws4[4];
    if ((t & 63) == 0) ws4[t >> 6] = v;
    __syncthreads();
    if (t == 0) chunksum[b] = ws4[0] + ws4[1] + ws4[2] + ws4[3];
}

// K2: exclusive scan of 256 chunk sums + total. One tiny block.
__global__ __launch_bounds__(256) void scan_chunks_kernel(const int* __restrict__ chunksum,
                                                          int* __restrict__ chunkoff,
                                                          int* __restrict__ totalp) {
    __shared__ int s[NCHUNK];
    const int t = threadIdx.x;
    const int v = chunksum[t];
    s[t] = v;
    __syncthreads();
    for (int off = 1; off < NCHUNK; off <<= 1) {
        int add = (t >= off) ? s[t - off] : 0;
        __syncthreads();
        s[t] += add;
        __syncthreads();
    }
    chunkoff[t] = s[t] - v;            // exclusive prefix
    if (t == NCHUNK - 1) totalp[0] = s[t];
}

// K3: per-chunk local scan + write idx16 spans. 256 blocks x 256 threads.
// Thread t owns source row i = b*256+t and writes its run [end-r, end) of
// ushort row indices (total ~458 KB of writes, L2-absorbed).
__global__ __launch_bounds__(256) void build_idx_kernel(const int* __restrict__ rep,
                                                        const int* __restrict__ chunkoff,
                                                        unsigned short* __restrict__ idx16,
                                                        int S) {
    const int b = blockIdx.x;
    const int t = threadIdx.x;
    const int i = b * CHUNK + t;
    const int r = rep[i];
    __shared__ int s[CHUNK];
    s[t] = r;
    __syncthreads();
    for (int off = 1; off < CHUNK; off <<= 1) {
        int add = (t >= off) ? s[t - off] : 0;
        __syncthreads();
        s[t] += add;
        __syncthreads();
    }
    int end = chunkoff[b] + s[t];
    const int start = end - r;
    if (start >= S) return;
    if (end > S) end = S;
    for (int j = start; j < end; ++j) idx16[j] = (unsigned short)i;
}

// ---------------------------------------------------------------------------
// K4: gather. One wave per FOUR output rows. Batch all 8 row-loads, then all
// 8 row-stores: 8 KB same-direction bursts instead of 2 KB alternation ->
// fewer HBM read/write turnarounds. XCD-aware block swizzle keeps adjacent
// output rows (which share a source row ~3.5x) on the same XCD's L2.
// Plain (cached) stores — nt measured slower in round 1->2.
// ---------------------------------------------------------------------------
__global__ __launch_bounds__(256) void gather_kernel(const f32x4* __restrict__ feeds,
                                                     const unsigned short* __restrict__ idx16,
                                                     const int* __restrict__ totalp,
                                                     f32x4* __restrict__ out,
                                                     int S) {
    // Bijective XCD swizzle: grid = S/16 = 16384 blocks, divisible by 8.
    int bid = blockIdx.x;
    const int cpx = gridDim.x >> 3;
    bid = (bid & 7) * cpx + (bid >> 3);

    const int wave = bid * 4 + (threadIdx.x >> 6);
    const int lane = threadIdx.x & 63;
    const int j0 = wave * 4;              // first of 4 output rows
    if (j0 >= S) return;

    const int total = totalp[0];

    f32x4 a[4], b[4];
#pragma unroll
    for (int q = 0; q < 4; ++q) {
        const int j = j0 + q;
        if (j < total) {
            const int si = idx16[j];
            const f32x4* src = feeds + (long long)si * D4;
            a[q] = src[lane];
            b[q] = src[lane + 64];
        } else {
            a[q] = (f32x4)0.f;
            b[q] = (f32x4)0.f;
        }
    }
#pragma unroll
    for (int q = 0; q < 4; ++q) {
        f32x4* dst = out + (long long)(j0 + q) * D4;
        dst[lane]      = a[q];
        dst[lane + 64] = b[q];
    }
}

extern "C" void kernel_launch(void* const* d_in, const int* in_sizes, int n_in,
                              void* d_out, int out_size, void* d_ws, size_t ws_size,
                              hipStream_t stream) {
    const float* feeds = (const float*)d_in[0];
    const int*   rep   = (const int*)d_in[1];
    const int S = out_size / DCOLS;

    int* ws       = (int*)d_ws;
    int* chunksum = ws;            // 256 ints
    int* chunkoff = ws + 256;      // 256 ints
    int* totalp   = ws + 512;      // 1 int
    unsigned short* idx16 = (unsigned short*)(ws + 1024);  // S ushorts = 512 KB

    chunk_sum_kernel<<<NCHUNK, CHUNK, 0, stream>>>(rep, chunksum);
    scan_chunks_kernel<<<1, NCHUNK, 0, stream>>>(chunksum, chunkoff, totalp);
    build_idx_kernel<<<NCHUNK, CHUNK, 0, stream>>>(rep, chunkoff, idx16, S);
    // 16 output rows per block (4 waves x 4 rows) -> S/16 = 16384 blocks.
    gather_kernel<<<S / 16, 256, 0, stream>>>((const f32x4*)feeds, idx16, totalp,
                                              (f32x4*)d_out, S);
}